// Round 3
// baseline (729.148 us; speedup 1.0000x reference)
//
#include <hip/hip_runtime.h>

#define N_NODES 50000
#define N_EDGES 800000

typedef unsigned int u32;
typedef unsigned short u16;

__device__ __forceinline__ float bf_lo(u32 v){ return __uint_as_float(v << 16); }
__device__ __forceinline__ float bf_hi(u32 v){ return __uint_as_float(v & 0xffff0000u); }
__device__ __forceinline__ u16 f2bf(float f){
    u32 u = __float_as_uint(f);
    u += 0x7fffu + ((u >> 16) & 1u);     // round-to-nearest-even
    return (u16)(u >> 16);
}

// ---------------------------------------------------------------- zero counts
__global__ void zero_cnt_kernel(u32* __restrict__ cnt){
    int i = blockIdx.x * 1024 + threadIdx.x;
    if (i < 2 * N_NODES) cnt[i] = 0u;
}

// ------------------------------------------------------- pack weights to bf16
// Wcat1[k][256] = [w_e1 top | w_e1 bottom]  (for A|B)
// Wcat2[k][256] = [w_s2d | w_d2s]           (for xs2d|xd2s)
__global__ void prep_kernel(const float* __restrict__ w_s2d, const float* __restrict__ w_d2s,
                            const float* __restrict__ w_e1, const float* __restrict__ w_g1,
                            const float* __restrict__ b_e1, const float* __restrict__ b_s2d,
                            const float* __restrict__ b_d2s,
                            u16* __restrict__ Wcat1, u16* __restrict__ Wcat2,
                            u16* __restrict__ Wg1b, float* __restrict__ bias1, float* __restrict__ bias2){
    int idx = blockIdx.x * 256 + threadIdx.x;
    if (idx < 32768){
        int k = idx >> 8, o = idx & 255;
        float v = (o < 128) ? w_e1[k * 128 + o] : w_e1[(128 + k) * 128 + (o - 128)];
        Wcat1[idx] = f2bf(v);
    } else if (idx < 65536){
        int j = idx - 32768, k = j >> 8, o = j & 255;
        float v = (o < 128) ? w_s2d[k * 128 + o] : w_d2s[k * 128 + (o - 128)];
        Wcat2[j] = f2bf(v);
    } else if (idx < 98304){
        int j = idx - 65536;
        Wg1b[j] = f2bf(w_g1[j]);
    } else if (idx < 98560){
        int o = idx - 98304;
        bias1[o] = (o < 128) ? b_e1[o] : 0.f;
    } else if (idx < 98816){
        int o = idx - 98560;
        bias2[o] = (o < 128) ? b_s2d[o] : b_d2s[o - 128];
    }
}

// ------------------------------------------- node projections (one 256-phase)
// T[node][128 u32] bf16-pairs = x[node] @ Wcat + bias   (256 outputs)
__global__ __launch_bounds__(256) void proj_kernel(const float* __restrict__ x,
        const u16* __restrict__ Wcat, const float* __restrict__ bias,
        u32* __restrict__ T){
    __shared__ float xs[32 * 132];
    const int tid = threadIdx.x;
    const int nb = blockIdx.x * 32;
    #pragma unroll
    for (int i = 0; i < 16; i++){
        int li = tid + i * 256;
        int nn = li >> 7, k = li & 127;
        int g = nb + nn;
        xs[nn * 132 + k] = (g < N_NODES) ? x[g * 128 + k] : 0.f;
    }
    __syncthreads();
    const int og = tid & 15, ng = tid >> 4;
    const int o0 = og * 16, n0 = ng * 2;
    float acc[2][16];
    #pragma unroll
    for (int j = 0; j < 2; j++)
        #pragma unroll
        for (int i = 0; i < 16; i++) acc[j][i] = 0.f;

    for (int k = 0; k < 128; k++){
        const uint4 wa = *(const uint4*)(Wcat + k * 256 + o0);
        const uint4 wb = *(const uint4*)(Wcat + k * 256 + o0 + 8);
        u32 w32[8] = {wa.x, wa.y, wa.z, wa.w, wb.x, wb.y, wb.z, wb.w};
        float wf[16];
        #pragma unroll
        for (int m = 0; m < 8; m++){ wf[2*m] = bf_lo(w32[m]); wf[2*m+1] = bf_hi(w32[m]); }
        float xv0 = xs[n0 * 132 + k];
        float xv1 = xs[(n0 + 1) * 132 + k];
        #pragma unroll
        for (int i = 0; i < 16; i++){ acc[0][i] += xv0 * wf[i]; acc[1][i] += xv1 * wf[i]; }
    }
    #pragma unroll
    for (int j = 0; j < 2; j++){
        int g = nb + n0 + j;
        if (g >= N_NODES) continue;
        u32 w32o[8];
        #pragma unroll
        for (int m = 0; m < 8; m++){
            u16 lo = f2bf(acc[j][2*m]   + bias[o0 + 2*m]);
            u16 hi = f2bf(acc[j][2*m+1] + bias[o0 + 2*m+1]);
            w32o[m] = (u32)lo | ((u32)hi << 16);
        }
        uint4* dst = (uint4*)(T + g * 128 + og * 8);
        dst[0] = make_uint4(w32o[0], w32o[1], w32o[2], w32o[3]);
        dst[1] = make_uint4(w32o[4], w32o[5], w32o[6], w32o[7]);
    }
}

// ------------------------------------------- edge scores + degree histograms
// T holds [A|B]: A = words 0..63 (elems 2l,2l+1), B = words 64..127
__global__ __launch_bounds__(256) void edge_score_kernel(const u32* __restrict__ T, const int* __restrict__ eidx,
        const float* __restrict__ w_e2, const float* __restrict__ b_e2,
        u16* __restrict__ score, u32* __restrict__ cnt_dst, u32* __restrict__ cnt_src){
    const int wave = threadIdx.x >> 6, lane = threadIdx.x & 63;
    const int e = blockIdx.x * 4 + wave;
    if (e >= N_EDGES) return;
    const int src = eidx[e];
    const int dst = eidx[N_EDGES + e];
    const u32 av = T[src * 128 + lane];
    const u32 bv = T[dst * 128 + 64 + lane];
    const float2 w = ((const float2*)w_e2)[lane];
    float h0 = fmaxf(bf_lo(av) + bf_lo(bv), 0.f);
    float h1 = fmaxf(bf_hi(av) + bf_hi(bv), 0.f);
    float p = h0 * w.x + h1 * w.y;
    #pragma unroll
    for (int m = 32; m >= 1; m >>= 1) p += __shfl_xor(p, m, 64);
    if (lane == 0){
        float sc = 1.f / (1.f + __expf(-(p + b_e2[0])));
        score[e] = f2bf(sc);
        atomicAdd(cnt_dst + dst, 1u);
        atomicAdd(cnt_src + src, 1u);
    }
}

// ------------------------------------------------------- exclusive scan (x2)
__global__ __launch_bounds__(1024) void scan_kernel(const u32* __restrict__ cnt,
        u32* __restrict__ start_dst, u32* __restrict__ next_dst,
        u32* __restrict__ start_src, u32* __restrict__ next_src){
    __shared__ u32 sa[1024], sb[1024];
    const int t = threadIdx.x;
    const u32* c = cnt + (blockIdx.x ? N_NODES : 0);
    u32* st = blockIdx.x ? start_src : start_dst;
    u32* nx = blockIdx.x ? next_src  : next_dst;
    const int CH = 49;                       // 1024*49 = 50176 >= N
    const int base = t * CH;
    u32 s = 0;
    for (int j = 0; j < CH; j++){ int i = base + j; if (i < N_NODES) s += c[i]; }
    sa[t] = s; __syncthreads();
    u32* a = sa; u32* b = sb;
    for (int off = 1; off < 1024; off <<= 1){
        u32 v = a[t];
        if (t >= off) v += a[t - off];
        b[t] = v;
        __syncthreads();
        u32* tmp = a; a = b; b = tmp;
    }
    u32 run = (t == 0) ? 0u : a[t - 1];
    for (int j = 0; j < CH; j++){
        int i = base + j;
        if (i < N_NODES){ st[i] = run; nx[i] = run; run += c[i]; }
    }
}

// ------------------------------------------------- scatter edge payloads CSR
// payload u32: [score bf16 in high 16 | neighbor id in low 16]  (N < 65536)
__global__ __launch_bounds__(256) void scatter_kernel(const int* __restrict__ eidx, const u16* __restrict__ score,
        u32* __restrict__ next_dst, u32* __restrict__ next_src,
        u32* __restrict__ in_pay, u32* __restrict__ out_pay){
    int e = blockIdx.x * 256 + threadIdx.x;
    if (e >= N_EDGES) return;
    int src = eidx[e], dst = eidx[N_EDGES + e];
    u32 sc = (u32)score[e] << 16;
    u32 p1 = atomicAdd(next_dst + dst, 1u);
    in_pay[p1] = sc | (u32)src;
    u32 p2 = atomicAdd(next_src + src, 1u);
    out_pay[p2] = sc | (u32)dst;
}

// ----------------------------------------- gather + degree-normalize h_in/out
// T holds [xs2d|xd2s]: xs2d = words 0..63, xd2s = words 64..127
// h_in / h_out bf16-packed: u32 word l of node = elems {2l, 2l+1}
__global__ __launch_bounds__(256) void gather_kernel(const u32* __restrict__ T,
        const u32* __restrict__ in_pay, const u32* __restrict__ out_pay,
        const u32* __restrict__ cnt_dst, const u32* __restrict__ start_dst,
        const u32* __restrict__ cnt_src, const u32* __restrict__ start_src,
        u32* __restrict__ h_in, u32* __restrict__ h_out){
    const int wave = threadIdx.x >> 6, lane = threadIdx.x & 63;
    const int node = blockIdx.x * 4 + wave;
    if (node >= N_NODES) return;
    {
        u32 deg = cnt_dst[node], st = start_dst[node];
        float a0 = 0.f, a1 = 0.f;
        u32 j = 0;
        for (; j + 4 <= deg; j += 4){
            u32 p0 = in_pay[st+j], p1 = in_pay[st+j+1], p2 = in_pay[st+j+2], p3 = in_pay[st+j+3];
            u32 v0 = T[(p0 & 0xffffu)*128 + lane], v1 = T[(p1 & 0xffffu)*128 + lane];
            u32 v2 = T[(p2 & 0xffffu)*128 + lane], v3 = T[(p3 & 0xffffu)*128 + lane];
            float s0 = __uint_as_float(p0 & 0xffff0000u), s1 = __uint_as_float(p1 & 0xffff0000u);
            float s2 = __uint_as_float(p2 & 0xffff0000u), s3 = __uint_as_float(p3 & 0xffff0000u);
            a0 += s0*bf_lo(v0) + s1*bf_lo(v1) + s2*bf_lo(v2) + s3*bf_lo(v3);
            a1 += s0*bf_hi(v0) + s1*bf_hi(v1) + s2*bf_hi(v2) + s3*bf_hi(v3);
        }
        for (; j < deg; j++){
            u32 pl = in_pay[st + j];
            u32 v = T[(pl & 0xffffu)*128 + lane];
            float sc = __uint_as_float(pl & 0xffff0000u);
            a0 += sc * bf_lo(v); a1 += sc * bf_hi(v);
        }
        float inv = 1.f / fmaxf((float)deg, 1.f);
        h_in[node * 64 + lane] = (u32)f2bf(a0 * inv) | ((u32)f2bf(a1 * inv) << 16);
    }
    {
        u32 deg = cnt_src[node], st = start_src[node];
        float a0 = 0.f, a1 = 0.f;
        u32 j = 0;
        for (; j + 4 <= deg; j += 4){
            u32 p0 = out_pay[st+j], p1 = out_pay[st+j+1], p2 = out_pay[st+j+2], p3 = out_pay[st+j+3];
            u32 v0 = T[(p0 & 0xffffu)*128 + 64 + lane], v1 = T[(p1 & 0xffffu)*128 + 64 + lane];
            u32 v2 = T[(p2 & 0xffffu)*128 + 64 + lane], v3 = T[(p3 & 0xffffu)*128 + 64 + lane];
            float s0 = __uint_as_float(p0 & 0xffff0000u), s1 = __uint_as_float(p1 & 0xffff0000u);
            float s2 = __uint_as_float(p2 & 0xffff0000u), s3 = __uint_as_float(p3 & 0xffff0000u);
            a0 += s0*bf_lo(v0) + s1*bf_lo(v1) + s2*bf_lo(v2) + s3*bf_lo(v3);
            a1 += s0*bf_hi(v0) + s1*bf_hi(v1) + s2*bf_hi(v2) + s3*bf_hi(v3);
        }
        for (; j < deg; j++){
            u32 pl = out_pay[st + j];
            u32 v = T[(pl & 0xffffu)*128 + 64 + lane];
            float sc = __uint_as_float(pl & 0xffff0000u);
            a0 += sc * bf_lo(v); a1 += sc * bf_hi(v);
        }
        float inv = 1.f / fmaxf((float)deg, 1.f);
        h_out[node * 64 + lane] = (u32)f2bf(a0 * inv) | ((u32)f2bf(a1 * inv) << 16);
    }
}

// ------------------------------------------------- gate MLP + fuse + residual
__global__ __launch_bounds__(256) void gate_kernel(const u16* __restrict__ h_in, const u16* __restrict__ h_out,
        const float* __restrict__ x, const u16* __restrict__ Wg1b, const float* __restrict__ b_g1,
        const float* __restrict__ w_g2, const float* __restrict__ b_g2, float* __restrict__ out){
    __shared__ float gin[32 * 256];
    __shared__ float part[32 * 33];
    __shared__ float gl[32];
    const int tid = threadIdx.x;
    const int nb = blockIdx.x * 32;
    #pragma unroll
    for (int i = 0; i < 16; i++){
        int li = tid + i * 256;           // 0..4095
        int nn = li >> 7, k = li & 127;
        int g = nb + nn;
        float vi = (g < N_NODES) ? __uint_as_float((u32)h_in [g * 128 + k] << 16) : 0.f;
        float vo = (g < N_NODES) ? __uint_as_float((u32)h_out[g * 128 + k] << 16) : 0.f;
        gin[nn * 256 + k] = vi;
        gin[nn * 256 + 128 + k] = vo;
    }
    __syncthreads();
    const int og = tid & 31, ng = tid >> 5;
    const int o0 = og * 4, n0 = ng * 4;
    float acc[4][4] = {};
    for (int k = 0; k < 256; k++){
        uint2 wv = *(const uint2*)(Wg1b + k * 128 + o0);
        float wf0 = bf_lo(wv.x), wf1 = bf_hi(wv.x), wf2 = bf_lo(wv.y), wf3 = bf_hi(wv.y);
        #pragma unroll
        for (int j = 0; j < 4; j++){
            float xv = gin[(n0 + j) * 256 + k];
            acc[j][0] += xv * wf0; acc[j][1] += xv * wf1;
            acc[j][2] += xv * wf2; acc[j][3] += xv * wf3;
        }
    }
    float bg[4], w2[4];
    #pragma unroll
    for (int i = 0; i < 4; i++){ bg[i] = b_g1[o0 + i]; w2[i] = w_g2[o0 + i]; }
    #pragma unroll
    for (int j = 0; j < 4; j++){
        float p = 0.f;
        #pragma unroll
        for (int i = 0; i < 4; i++) p += fmaxf(acc[j][i] + bg[i], 0.f) * w2[i];
        part[(n0 + j) * 33 + og] = p;
    }
    __syncthreads();
    if (tid < 32){
        float s = 0.f;
        for (int i = 0; i < 32; i++) s += part[tid * 33 + i];
        gl[tid] = 1.f / (1.f + __expf(-(s + b_g2[0])));
    }
    __syncthreads();
    #pragma unroll
    for (int i = 0; i < 16; i++){
        int li = tid + i * 256;
        int nn = li >> 7, o = li & 127;
        int g = nb + nn;
        if (g < N_NODES){
            float gv = gl[nn];
            float hi = gin[nn * 256 + o], ho = gin[nn * 256 + 128 + o];
            out[g * 128 + o] = gv * hi + (1.f - gv) * ho + x[g * 128 + o];
        }
    }
}

extern "C" void kernel_launch(void* const* d_in, const int* in_sizes, int n_in,
                              void* d_out, int out_size, void* d_ws, size_t ws_size,
                              hipStream_t stream){
    const float* x     = (const float*)d_in[0];
    const int*   ei    = (const int*)d_in[1];          // int32 (JAX x64 off)
    const float* w_s2d = (const float*)d_in[2];
    const float* b_s2d = (const float*)d_in[3];
    const float* w_d2s = (const float*)d_in[4];
    const float* b_d2s = (const float*)d_in[5];
    const float* w_e1  = (const float*)d_in[6];
    const float* b_e1  = (const float*)d_in[7];
    const float* w_e2  = (const float*)d_in[8];
    const float* b_e2  = (const float*)d_in[9];
    const float* w_g1  = (const float*)d_in[10];
    const float* b_g1  = (const float*)d_in[11];
    const float* w_g2  = (const float*)d_in[12];
    const float* b_g2  = (const float*)d_in[13];
    float* out = (float*)d_out;
    u32*   T   = (u32*)d_out;                 // 50000*128 u32 = exactly out_size floats

    char* ws = (char*)d_ws;
    size_t off = 0;
    #define TAKE(name, bytes) char* name = ws + off; off += (((size_t)(bytes)) + 511) & ~(size_t)511;
    TAKE(Wcat1_b, 32768 * 2)
    TAKE(Wcat2_b, 32768 * 2)
    TAKE(Wg1b_b,  32768 * 2)
    TAKE(bias1_b, 256 * 4)
    TAKE(bias2_b, 256 * 4)
    TAKE(score_b, (size_t)N_EDGES * 2)
    TAKE(cnt_b,   (size_t)2 * N_NODES * 4)    // cnt_dst | cnt_src
    TAKE(sd_b,    (size_t)N_NODES * 4)
    TAKE(ss_b,    (size_t)N_NODES * 4)
    TAKE(nd_b,    (size_t)N_NODES * 4)
    TAKE(ns_b,    (size_t)N_NODES * 4)
    TAKE(ipay_b,  (size_t)N_EDGES * 4)
    TAKE(opay_b,  (size_t)N_EDGES * 4)
    TAKE(hin_b,   (size_t)N_NODES * 128 * 2)  // bf16
    TAKE(hout_b,  (size_t)N_NODES * 128 * 2)  // bf16
    #undef TAKE
    (void)ws_size; (void)in_sizes; (void)n_in; (void)out_size;
    // total ~22.2 MB

    zero_cnt_kernel<<<(2 * N_NODES + 1023) / 1024, 1024, 0, stream>>>((u32*)cnt_b);
    prep_kernel<<<(98816 + 255) / 256, 256, 0, stream>>>(w_s2d, w_d2s, w_e1, w_g1,
        b_e1, b_s2d, b_d2s,
        (u16*)Wcat1_b, (u16*)Wcat2_b, (u16*)Wg1b_b, (float*)bias1_b, (float*)bias2_b);
    // phase 1: T = [A|B]
    proj_kernel<<<(N_NODES + 31) / 32, 256, 0, stream>>>(x, (const u16*)Wcat1_b, (const float*)bias1_b, T);
    edge_score_kernel<<<N_EDGES / 4, 256, 0, stream>>>((const u32*)T, ei, w_e2, b_e2,
        (u16*)score_b, (u32*)cnt_b, (u32*)cnt_b + N_NODES);
    scan_kernel<<<2, 1024, 0, stream>>>((const u32*)cnt_b, (u32*)sd_b, (u32*)nd_b, (u32*)ss_b, (u32*)ns_b);
    scatter_kernel<<<N_EDGES / 256, 256, 0, stream>>>(ei, (const u16*)score_b,
        (u32*)nd_b, (u32*)ns_b, (u32*)ipay_b, (u32*)opay_b);
    // phase 2: T = [xs2d|xd2s]
    proj_kernel<<<(N_NODES + 31) / 32, 256, 0, stream>>>(x, (const u16*)Wcat2_b, (const float*)bias2_b, T);
    gather_kernel<<<N_NODES / 4, 256, 0, stream>>>((const u32*)T,
        (const u32*)ipay_b, (const u32*)opay_b,
        (const u32*)cnt_b, (const u32*)sd_b, (const u32*)cnt_b + N_NODES, (const u32*)ss_b,
        (u32*)hin_b, (u32*)hout_b);
    gate_kernel<<<(N_NODES + 31) / 32, 256, 0, stream>>>((const u16*)hin_b, (const u16*)hout_b,
        x, (const u16*)Wg1b_b, b_g1, w_g2, b_g2, out);
}